// Round 7
// baseline (81.550 us; speedup 1.0000x reference)
//
#include <hip/hip_runtime.h>
#include <hip/hip_bf16.h>

// Problem constants: B=4, Q=256, K=256, H=512
#define B_ 4
#define Q_ 256
#define K_ 256
#define H_ 512
#define NEG (-1e9f)
// 2*log2(e): exp2(PRESCALE*x) = e^{2x}
#define PRESCALE 2.885390081777927f

// ---------------------------------------------------------------------------
// Kernel 1: fp32 projection GEMM + EXP epilogue, W via wave-uniform s_loads.
// Output rows 0..1023:  query@Wq -> Eq[b][q][h] = exp2(PRESCALE*.)  row-major
// rows 1024..2047: key@Wk -> EkT[b][h][k] = exp2(PRESCALE*.)  transposed
//
// grid = (32 row-tiles of 64, 16 col-tiles of 32), block = 128 (2 waves).
// Wave layout: lane = row (64 rows/block), wave w owns cols [col0+16w, +16).
//   acc[16] per thread; per k: x = Xs[lane][k] (LDS b32, bank (row+k)%32 =
//   conflict-free), W[k][c..c+15] wave-uniform -> s_load (scalar pipe, no LDS,
//   no VGPR). 16 v_fmac(v,s,v) per k -> VALU-bound (~6.8 us floor).
// X staged in 64x64 chunks, reg-prefetched (global load issued before compute
// of previous chunk). Masked key tiles (k0 >= valid_len) skipped.
// ---------------------------------------------------------------------------
__global__ __launch_bounds__(128) void proj_kernel(
    const float* __restrict__ Xq, const float* __restrict__ Xk,
    const float* __restrict__ Wq, const float* __restrict__ Wk,
    float* __restrict__ Eq, float* __restrict__ EkT,
    const int* __restrict__ vlen)
{
    const int bx   = blockIdx.x;          // 0..31
    const int z    = bx >> 4;             // 0 = q, 1 = k
    const int row0 = (bx & 15) * 64;      // global row of X (q or k block)
    if (z) {
        const int bb = row0 >> 8, k0 = row0 & 255;
        if (k0 >= vlen[bb]) return;       // masked kp cols never read downstream
    }
    const float* X = z ? Xk : Xq;
    const float* W = z ? Wk : Wq;

    __shared__ float Xs[64][65];          // pad 65: read bank = (row+k)%32, free

    const int col0 = blockIdx.y * 32;
    const int t    = threadIdx.x;
    const int lane = t & 63;              // = row within tile
    // wave-uniform column base (readfirstlane -> SGPR -> s_load chain for W)
    const int wv     = __builtin_amdgcn_readfirstlane(t >> 6);   // 0 or 1
    const int wcol0  = col0 + 16 * wv;

    // staging mapping: 1024 float4/chunk, 8 per thread
    const int srow0 = t >> 4;             // + 8*l
    const int sk    = (t & 15) * 4;       // k offset (float4)

    float acc[16] = {};

    // prologue: load chunk 0 into registers
    float4 st[8];
    #pragma unroll
    for (int l = 0; l < 8; ++l)
        st[l] = *(const float4*)&X[(size_t)(row0 + srow0 + 8 * l) * H_ + sk];

    for (int c = 0; c < 8; ++c) {
        __syncthreads();                  // prior chunk's LDS reads done
        #pragma unroll
        for (int l = 0; l < 8; ++l) {
            const int r = srow0 + 8 * l;
            Xs[r][sk + 0] = st[l].x;
            Xs[r][sk + 1] = st[l].y;
            Xs[r][sk + 2] = st[l].z;
            Xs[r][sk + 3] = st[l].w;
        }
        __syncthreads();
        if (c < 7) {                      // prefetch next chunk (hidden by compute)
            const int kc = (c + 1) * 64;
            #pragma unroll
            for (int l = 0; l < 8; ++l)
                st[l] = *(const float4*)&X[(size_t)(row0 + srow0 + 8 * l) * H_ + kc + sk];
        }
        // compute 64 k of this chunk
        const float* wb = W + (size_t)c * 64 * H_ + wcol0;
        #pragma unroll 4
        for (int k = 0; k < 64; ++k) {
            const float x = Xs[lane][k];
            const float* wr = wb + (size_t)k * H_;      // wave-uniform
            #pragma unroll
            for (int c4 = 0; c4 < 4; ++c4) {
                const float4 w = *(const float4*)(wr + c4 * 4);
                acc[c4 * 4 + 0] = __builtin_fmaf(x, w.x, acc[c4 * 4 + 0]);
                acc[c4 * 4 + 1] = __builtin_fmaf(x, w.y, acc[c4 * 4 + 1]);
                acc[c4 * 4 + 2] = __builtin_fmaf(x, w.z, acc[c4 * 4 + 2]);
                acc[c4 * 4 + 3] = __builtin_fmaf(x, w.w, acc[c4 * 4 + 3]);
            }
        }
    }

    if (!z) {
        // Eq[(row0+lane)*H + wcol0 + c] = exp2(PRESCALE*acc[c])
        float* dst = &Eq[(size_t)(row0 + lane) * H_ + wcol0];
        #pragma unroll
        for (int c4 = 0; c4 < 4; ++c4) {
            float4 o = make_float4(
                __builtin_amdgcn_exp2f(acc[c4 * 4 + 0] * PRESCALE),
                __builtin_amdgcn_exp2f(acc[c4 * 4 + 1] * PRESCALE),
                __builtin_amdgcn_exp2f(acc[c4 * 4 + 2] * PRESCALE),
                __builtin_amdgcn_exp2f(acc[c4 * 4 + 3] * PRESCALE));
            *(float4*)(dst + c4 * 4) = o;
        }
    } else {
        // EkT[(b*H + h)*K + k]: lane = k -> consecutive-k b32 stores (coalesced)
        const int bb = row0 >> 8, k0 = row0 & 255;
        const int kg = k0 + lane;
        #pragma unroll
        for (int c = 0; c < 16; ++c)
            EkT[((size_t)bb * H_ + wcol0 + c) * K_ + kg] =
                __builtin_amdgcn_exp2f(acc[c] * PRESCALE);
    }
}

// ---------------------------------------------------------------------------
// Kernel 2: fused scores -> masked softmax -> context.
// grid = (Q/2, B) = (128, 4), block = 512 (8 waves) -> 2 blocks/CU.
// Score phase: wave w owns k-band [32w,32w+32), whole-wave skip if >= valid.
//   lane = (ho = lane>>3, kg = lane&7); thread owns 2 q x 4 k, h-slice
//   {ho+8s}. Ek b128 global loads with explicit 4-deep register prefetch
//   (group g+1 issued before computing group g -> L2 latency hidden).
//   acc = fma(wm, rcp(fma(eq, ek, 1)), acc); 3 shfl_xor fold ho groups.
// Softmax: waves 0,1. Context: wave w owns its 32-k band, LDS tree reduce.
// ---------------------------------------------------------------------------
__global__ __launch_bounds__(512) void fused_attn(
    const float* __restrict__ Eq, const float* __restrict__ EkT,
    const float* __restrict__ value, const int* __restrict__ vlen,
    const float* __restrict__ wv, float* __restrict__ out)
{
    const int qt = blockIdx.x;        // 0..127
    const int b  = blockIdx.y;        // 0..3
    const int q0 = qt * 2;
    const int t    = threadIdx.x;
    const int wave = t >> 6;          // 0..7
    const int lane = t & 63;

    __shared__ float eqh[H_][2];      // 4 KB  [h][qi]
    __shared__ float wm[H_];          // 2 KB  (-2 * wv)
    __shared__ float sc[2][K_];       // 2 KB
    __shared__ float ctxp[4][2][H_];  // 16 KB reduce scratch

    const int valid = vlen[b];

    // ---- one-time staging: eqh (transposed) + wm ----
    if (t < 256) {
        const int qi = t >> 7, p4 = (t & 127) * 4;
        const float4 v = *(const float4*)&Eq[((size_t)b * Q_ + q0 + qi) * H_ + p4];
        eqh[p4 + 0][qi] = v.x; eqh[p4 + 1][qi] = v.y;
        eqh[p4 + 2][qi] = v.z; eqh[p4 + 3][qi] = v.w;
    } else if (t < 384) {
        const int i = (t - 256) * 4;
        const float4 w = *(const float4*)&wv[i];
        *(float4*)&wm[i] = make_float4(-2.f * w.x, -2.f * w.y, -2.f * w.z, -2.f * w.w);
    }
    __syncthreads();

    // ---- score phase ----
    const int band = wave * 32;
    const int ho   = lane >> 3;       // h offset 0..7
    const int kg   = lane & 7;        // k group 0..7
    const int kq   = band + kg * 4;   // this thread's first k

    if (band < valid) {
        const float* ekp = EkT + ((size_t)b * H_ + ho) * K_ + kq;
        float a0[4] = {}, a1[4] = {};
        float4 pe[4], ne[4];
        #pragma unroll
        for (int p = 0; p < 4; ++p)
            pe[p] = *(const float4*)(ekp + (size_t)p * 8 * K_);

        for (int g = 0; g < 16; ++g) {        // 16 groups x 4 h-steps
            if (g < 15) {
                #pragma unroll
                for (int p = 0; p < 4; ++p)
                    ne[p] = *(const float4*)(ekp + (size_t)((g + 1) * 4 + p) * 8 * K_);
            }
            #pragma unroll
            for (int p = 0; p < 4; ++p) {
                const int h = ho + 8 * (g * 4 + p);
                const float2 eq = *(const float2*)&eqh[h][0];
                const float  w  = wm[h];
                const float ek4[4] = {pe[p].x, pe[p].y, pe[p].z, pe[p].w};
                #pragma unroll
                for (int j = 0; j < 4; ++j) {
                    const float g0 = __builtin_fmaf(eq.x, ek4[j], 1.0f);
                    a0[j] = __builtin_fmaf(w, __builtin_amdgcn_rcpf(g0), a0[j]);
                    const float g1 = __builtin_fmaf(eq.y, ek4[j], 1.0f);
                    a1[j] = __builtin_fmaf(w, __builtin_amdgcn_rcpf(g1), a1[j]);
                }
            }
            if (g < 15) {
                #pragma unroll
                for (int p = 0; p < 4; ++p) pe[p] = ne[p];
            }
        }
        // combine h-partials across ho groups (lane bits 3..5)
        #pragma unroll
        for (int d = 8; d < 64; d <<= 1) {
            #pragma unroll
            for (int j = 0; j < 4; ++j) {
                a0[j] += __shfl_xor(a0[j], d);
                a1[j] += __shfl_xor(a1[j], d);
            }
        }
        if (ho == 0) {
            *(float4*)&sc[0][kq] = make_float4(a0[0], a0[1], a0[2], a0[3]);
            *(float4*)&sc[1][kq] = make_float4(a1[0], a1[1], a1[2], a1[3]);
        }
    }
    __syncthreads();

    // ---- masked softmax (waves 0,1; row = wave) ----
    if (wave < 2) {
        const int q = wave;
        if (valid == 0) {
            #pragma unroll
            for (int j = 0; j < 4; ++j) sc[q][lane + 64 * j] = 1.0f / K_;
        } else {
            float sv[4], mx = -3e38f;
            #pragma unroll
            for (int j = 0; j < 4; ++j) {
                const int kk = lane + 64 * j;
                const float s = (kk < valid) ? sc[q][kk] : NEG;
                sv[j] = s;
                mx = fmaxf(mx, s);
            }
            #pragma unroll
            for (int d = 32; d; d >>= 1) mx = fmaxf(mx, __shfl_xor(mx, d));
            float ev[4], sum = 0.f;
            #pragma unroll
            for (int j = 0; j < 4; ++j) { ev[j] = __expf(sv[j] - mx); sum += ev[j]; }
            #pragma unroll
            for (int d = 32; d; d >>= 1) sum += __shfl_xor(sum, d);
            const float inv = 1.0f / sum;
            #pragma unroll
            for (int j = 0; j < 4; ++j) sc[q][lane + 64 * j] = ev[j] * inv;
        }
    }
    __syncthreads();

    // ---- context: wave w owns k in [32w, 32w+32) ----
    const int klim = (valid == 0) ? K_ : valid;
    const int kb   = wave * 32;
    const int kend = min(32, klim - kb);
    const int h0   = lane * 8;

    float c0[8] = {}, c1[8] = {};
    for (int kc = 0; kc < kend; ++kc) {
        const int kk = kb + kc;
        const float4* vp = (const float4*)&value[((size_t)b * K_ + kk) * H_ + h0];
        const float4 v0 = vp[0], v1 = vp[1];
        const float vr[8] = {v0.x, v0.y, v0.z, v0.w, v1.x, v1.y, v1.z, v1.w};
        const float a0 = sc[0][kk], a1 = sc[1][kk];
        #pragma unroll
        for (int j = 0; j < 8; ++j) {
            c0[j] = __builtin_fmaf(a0, vr[j], c0[j]);
            c1[j] = __builtin_fmaf(a1, vr[j], c1[j]);
        }
    }

    // 3-level tree reduce over 8 waves
    #define PARK(s)                                                         \
        do {                                                                \
            float* d0 = &ctxp[s][0][h0];                                    \
            float* d1 = &ctxp[s][1][h0];                                    \
            ((float4*)d0)[0] = make_float4(c0[0], c0[1], c0[2], c0[3]);     \
            ((float4*)d0)[1] = make_float4(c0[4], c0[5], c0[6], c0[7]);     \
            ((float4*)d1)[0] = make_float4(c1[0], c1[1], c1[2], c1[3]);     \
            ((float4*)d1)[1] = make_float4(c1[4], c1[5], c1[6], c1[7]);     \
        } while (0)
    #define FOLD(s)                                                         \
        do {                                                                \
            const float* d0 = &ctxp[s][0][h0];                              \
            const float* d1 = &ctxp[s][1][h0];                              \
            _Pragma("unroll")                                               \
            for (int j = 0; j < 8; ++j) { c0[j] += d0[j]; c1[j] += d1[j]; } \
        } while (0)

    if (wave >= 4) PARK(wave - 4);
    __syncthreads();
    if (wave < 4) FOLD(wave);
    __syncthreads();
    if (wave == 2 || wave == 3) PARK(wave - 2);
    __syncthreads();
    if (wave < 2) FOLD(wave);
    __syncthreads();
    if (wave == 1) PARK(1);
    __syncthreads();
    if (wave == 0) {
        FOLD(1);
        float* o0 = &out[((size_t)b * Q_ + q0 + 0) * H_ + h0];
        float* o1 = &out[((size_t)b * Q_ + q0 + 1) * H_ + h0];
        ((float4*)o0)[0] = make_float4(c0[0], c0[1], c0[2], c0[3]);
        ((float4*)o0)[1] = make_float4(c0[4], c0[5], c0[6], c0[7]);
        ((float4*)o1)[0] = make_float4(c1[0], c1[1], c1[2], c1[3]);
        ((float4*)o1)[1] = make_float4(c1[4], c1[5], c1[6], c1[7]);
    }
    #undef PARK
    #undef FOLD
}

// ---------------------------------------------------------------------------
extern "C" void kernel_launch(void* const* d_in, const int* in_sizes, int n_in,
                              void* d_out, int out_size, void* d_ws, size_t ws_size,
                              hipStream_t stream)
{
    const float* query = (const float*)d_in[0];
    const float* key   = (const float*)d_in[1];
    const float* value = (const float*)d_in[2];
    const int*   vlen  = (const int*)  d_in[3];
    const float* Wq    = (const float*)d_in[4];
    const float* Wk    = (const float*)d_in[5];
    const float* wv    = (const float*)d_in[6];
    float*       outp  = (float*)d_out;

    float* EqBuf  = (float*)d_ws;                 // [B*Q, H] = 2 MB (e^{2q'})
    float* EkTBuf = EqBuf + (size_t)B_ * Q_ * H_; // [B, H, K] = 2 MB (e^{2k'}, transposed)

    dim3 g1(32, 16);                              // 512 blocks, 128 threads
    proj_kernel<<<g1, 128, 0, stream>>>(query, key, Wq, Wk, EqBuf, EkTBuf, vlen);

    dim3 g2(Q_ / 2, B_);                          // (128, 4), 512 threads
    fused_attn<<<g2, 512, 0, stream>>>(EqBuf, EkTBuf, value, vlen, wv, outp);
}

// Round 8
// 40.181 us; speedup vs baseline: 2.0296x; 2.0296x over previous
//
#include <hip/hip_runtime.h>
#include <hip/hip_bf16.h>

// Problem constants: B=4, Q=256, K=256, H=512
#define B_ 4
#define Q_ 256
#define K_ 256
#define H_ 512
#define NEG (-1e9f)
// 2*log2(e): exp2(PRESCALE*x) = e^{2x}
#define PRESCALE 2.885390081777927f

typedef _Float16 half8 __attribute__((ext_vector_type(8)));
typedef float    f32x4 __attribute__((ext_vector_type(4)));

// ---------------------------------------------------------------------------
// Kernel 1: f16 MFMA projection GEMM + EXP epilogue.
//   z=0: Eq[b][q][h]  = exp2(PRESCALE * (query@Wq))   row-major
//   z=1: EkT[b][h][k] = exp2(PRESCALE * (key@Wk))     transposed output
// 64x64 tile, K-step 32, 256 thr (4 waves), mfma_f32_16x16x32_f16.
// LDS: Xl[kg][row][8] f16 (X rows, 8 consecutive k), Wl[kg][col][8] f16
//   (W cols, 8 consecutive k = transposed W). Both padded to 65 rows.
// Fragment layout (gfx950, m89-verified): A/B: row|col = lane&15,
//   k = (lane>>4)*8 + j.  C/D: col = lane&15, row = (lane>>4)*4 + reg.
// z=1 swaps mfma operands: D = W^T-frag x X-frag -> D[h][k] -> EkT stores
//   are coalesced (lanes 0..15 = consecutive k). No LDS bounce needed.
// Masked key tiles (k0 >= valid_len[b]) skipped.
// ---------------------------------------------------------------------------
__global__ __launch_bounds__(256) void proj_kernel(
    const float* __restrict__ Xq, const float* __restrict__ Xk,
    const float* __restrict__ Wq, const float* __restrict__ Wk,
    float* __restrict__ Eq, float* __restrict__ EkT,
    const int* __restrict__ vlen)
{
    const int bx   = blockIdx.x;          // 0..31
    const int z    = bx >> 4;             // 0 = q, 1 = k
    const int row0 = (bx & 15) * 64;      // X row base (q-row or b*256+k)
    const int bb   = row0 >> 8;
    const int k0   = row0 & 255;
    if (z && k0 >= vlen[bb]) return;      // masked kp cols never read downstream

    const float* X = z ? Xk : Xq;
    const float* W = z ? Wk : Wq;

    // [kg 0..3][row 0..64(pad)][j 0..7], 520 f16 per kg-slab
    __shared__ _Float16 Xl[4 * 520];
    __shared__ _Float16 Wl[4 * 520];

    const int col0 = blockIdx.y * 64;     // W col base (= h base)
    const int t    = threadIdx.x;
    const int lane = t & 63;
    const int w    = t >> 6;              // wave 0..3 -> m-strip [16w,16w+16)
    const int m    = lane & 15;
    const int kgl  = lane >> 4;           // frag k-group

    // staging maps
    const int xr  = t >> 2;               // X row 0..63
    const int xkg = t & 3;                // X k-group
    const int wc  = t & 63;               // W col 0..63
    const int wkg = t >> 6;               // W k-group

    f32x4 acc[4] = {};                    // 4 n-tiles of 16

    // prologue: load k-chunk 0 into registers
    float4 xv0 = *(const float4*)&X[(size_t)(row0 + xr) * H_ + xkg * 8];
    float4 xv1 = *(const float4*)&X[(size_t)(row0 + xr) * H_ + xkg * 8 + 4];
    float wv8[8];
    #pragma unroll
    for (int i = 0; i < 8; ++i)
        wv8[i] = W[(size_t)(wkg * 8 + i) * H_ + col0 + wc];

    for (int it = 0; it < 16; ++it) {
        // store staged regs to LDS (f32 -> f16)
        {
            half8 hx;
            hx[0] = (_Float16)xv0.x; hx[1] = (_Float16)xv0.y;
            hx[2] = (_Float16)xv0.z; hx[3] = (_Float16)xv0.w;
            hx[4] = (_Float16)xv1.x; hx[5] = (_Float16)xv1.y;
            hx[6] = (_Float16)xv1.z; hx[7] = (_Float16)xv1.w;
            *(half8*)&Xl[xkg * 520 + xr * 8] = hx;
            half8 hw;
            #pragma unroll
            for (int i = 0; i < 8; ++i) hw[i] = (_Float16)wv8[i];
            *(half8*)&Wl[wkg * 520 + wc * 8] = hw;
        }
        __syncthreads();
        if (it < 15) {                    // prefetch next chunk (hidden by mfma)
            const int kk = (it + 1) * 32;
            xv0 = *(const float4*)&X[(size_t)(row0 + xr) * H_ + kk + xkg * 8];
            xv1 = *(const float4*)&X[(size_t)(row0 + xr) * H_ + kk + xkg * 8 + 4];
            #pragma unroll
            for (int i = 0; i < 8; ++i)
                wv8[i] = W[(size_t)(kk + wkg * 8 + i) * H_ + col0 + wc];
        }
        // compute: z=0: D[q][h] = X·W ; z=1: D[h][k] = W^T·X^T (swap operands)
        const _Float16* Asrc = z ? Wl : Xl;
        const _Float16* Bsrc = z ? Xl : Wl;
        const half8 af = *(const half8*)&Asrc[kgl * 520 + (16 * w + m) * 8];
        #pragma unroll
        for (int nt = 0; nt < 4; ++nt) {
            const half8 bf = *(const half8*)&Bsrc[kgl * 520 + (nt * 16 + m) * 8];
            acc[nt] = __builtin_amdgcn_mfma_f32_16x16x32_f16(af, bf, acc[nt], 0, 0, 0);
        }
        __syncthreads();
    }

    // epilogue: exp2(PRESCALE * acc), C/D layout col=lane&15 row=(lane>>4)*4+r
    if (!z) {
        #pragma unroll
        for (int nt = 0; nt < 4; ++nt) {
            const int gcol = col0 + nt * 16 + m;
            #pragma unroll
            for (int r = 0; r < 4; ++r) {
                const int grow = row0 + 16 * w + kgl * 4 + r;
                Eq[(size_t)grow * H_ + gcol] =
                    __builtin_amdgcn_exp2f(acc[nt][r] * PRESCALE);
            }
        }
    } else {
        #pragma unroll
        for (int nt = 0; nt < 4; ++nt) {
            const int gk = k0 + nt * 16 + m;      // D col = k (coalesced)
            #pragma unroll
            for (int r = 0; r < 4; ++r) {
                const int gh = col0 + 16 * w + kgl * 4 + r;  // D row = h
                EkT[((size_t)bb * H_ + gh) * K_ + gk] =
                    __builtin_amdgcn_exp2f(acc[nt][r] * PRESCALE);
            }
        }
    }
}

// ---------------------------------------------------------------------------
// Kernel 2: fused scores -> masked softmax -> context.  (unchanged from r7)
// grid = (Q/2, B) = (128, 4), block = 512 (8 waves) -> 2 blocks/CU.
// Score phase: wave w owns k-band [32w,32w+32), whole-wave skip if >= valid.
//   lane = (ho = lane>>3, kg = lane&7); thread owns 2 q x 4 k, h-slice
//   {ho+8s}. Ek b128 global loads with explicit 4-deep register prefetch.
//   acc = fma(wm, rcp(fma(eq, ek, 1)), acc); 3 shfl_xor fold ho groups.
// Softmax: waves 0,1. Context: wave w owns its 32-k band, LDS tree reduce.
// ---------------------------------------------------------------------------
__global__ __launch_bounds__(512) void fused_attn(
    const float* __restrict__ Eq, const float* __restrict__ EkT,
    const float* __restrict__ value, const int* __restrict__ vlen,
    const float* __restrict__ wv, float* __restrict__ out)
{
    const int qt = blockIdx.x;        // 0..127
    const int b  = blockIdx.y;        // 0..3
    const int q0 = qt * 2;
    const int t    = threadIdx.x;
    const int wave = t >> 6;          // 0..7
    const int lane = t & 63;

    __shared__ float eqh[H_][2];      // 4 KB  [h][qi]
    __shared__ float wm[H_];          // 2 KB  (-2 * wv)
    __shared__ float sc[2][K_];       // 2 KB
    __shared__ float ctxp[4][2][H_];  // 16 KB reduce scratch

    const int valid = vlen[b];

    // ---- one-time staging: eqh (transposed) + wm ----
    if (t < 256) {
        const int qi = t >> 7, p4 = (t & 127) * 4;
        const float4 v = *(const float4*)&Eq[((size_t)b * Q_ + q0 + qi) * H_ + p4];
        eqh[p4 + 0][qi] = v.x; eqh[p4 + 1][qi] = v.y;
        eqh[p4 + 2][qi] = v.z; eqh[p4 + 3][qi] = v.w;
    } else if (t < 384) {
        const int i = (t - 256) * 4;
        const float4 w = *(const float4*)&wv[i];
        *(float4*)&wm[i] = make_float4(-2.f * w.x, -2.f * w.y, -2.f * w.z, -2.f * w.w);
    }
    __syncthreads();

    // ---- score phase ----
    const int band = wave * 32;
    const int ho   = lane >> 3;       // h offset 0..7
    const int kg   = lane & 7;        // k group 0..7
    const int kq   = band + kg * 4;   // this thread's first k

    if (band < valid) {
        const float* ekp = EkT + ((size_t)b * H_ + ho) * K_ + kq;
        float a0[4] = {}, a1[4] = {};
        float4 pe[4], ne[4];
        #pragma unroll
        for (int p = 0; p < 4; ++p)
            pe[p] = *(const float4*)(ekp + (size_t)p * 8 * K_);

        for (int g = 0; g < 16; ++g) {        // 16 groups x 4 h-steps
            if (g < 15) {
                #pragma unroll
                for (int p = 0; p < 4; ++p)
                    ne[p] = *(const float4*)(ekp + (size_t)((g + 1) * 4 + p) * 8 * K_);
            }
            #pragma unroll
            for (int p = 0; p < 4; ++p) {
                const int h = ho + 8 * (g * 4 + p);
                const float2 eq = *(const float2*)&eqh[h][0];
                const float  w  = wm[h];
                const float ek4[4] = {pe[p].x, pe[p].y, pe[p].z, pe[p].w};
                #pragma unroll
                for (int j = 0; j < 4; ++j) {
                    const float g0 = __builtin_fmaf(eq.x, ek4[j], 1.0f);
                    a0[j] = __builtin_fmaf(w, __builtin_amdgcn_rcpf(g0), a0[j]);
                    const float g1 = __builtin_fmaf(eq.y, ek4[j], 1.0f);
                    a1[j] = __builtin_fmaf(w, __builtin_amdgcn_rcpf(g1), a1[j]);
                }
            }
            if (g < 15) {
                #pragma unroll
                for (int p = 0; p < 4; ++p) pe[p] = ne[p];
            }
        }
        // combine h-partials across ho groups (lane bits 3..5)
        #pragma unroll
        for (int d = 8; d < 64; d <<= 1) {
            #pragma unroll
            for (int j = 0; j < 4; ++j) {
                a0[j] += __shfl_xor(a0[j], d);
                a1[j] += __shfl_xor(a1[j], d);
            }
        }
        if (ho == 0) {
            *(float4*)&sc[0][kq] = make_float4(a0[0], a0[1], a0[2], a0[3]);
            *(float4*)&sc[1][kq] = make_float4(a1[0], a1[1], a1[2], a1[3]);
        }
    }
    __syncthreads();

    // ---- masked softmax (waves 0,1; row = wave) ----
    if (wave < 2) {
        const int q = wave;
        if (valid == 0) {
            #pragma unroll
            for (int j = 0; j < 4; ++j) sc[q][lane + 64 * j] = 1.0f / K_;
        } else {
            float sv[4], mx = -3e38f;
            #pragma unroll
            for (int j = 0; j < 4; ++j) {
                const int kk = lane + 64 * j;
                const float s = (kk < valid) ? sc[q][kk] : NEG;
                sv[j] = s;
                mx = fmaxf(mx, s);
            }
            #pragma unroll
            for (int d = 32; d; d >>= 1) mx = fmaxf(mx, __shfl_xor(mx, d));
            float ev[4], sum = 0.f;
            #pragma unroll
            for (int j = 0; j < 4; ++j) { ev[j] = __expf(sv[j] - mx); sum += ev[j]; }
            #pragma unroll
            for (int d = 32; d; d >>= 1) sum += __shfl_xor(sum, d);
            const float inv = 1.0f / sum;
            #pragma unroll
            for (int j = 0; j < 4; ++j) sc[q][lane + 64 * j] = ev[j] * inv;
        }
    }
    __syncthreads();

    // ---- context: wave w owns k in [32w, 32w+32) ----
    const int klim = (valid == 0) ? K_ : valid;
    const int kb   = wave * 32;
    const int kend = min(32, klim - kb);
    const int h0   = lane * 8;

    float c0[8] = {}, c1[8] = {};
    for (int kc = 0; kc < kend; ++kc) {
        const int kk = kb + kc;
        const float4* vp = (const float4*)&value[((size_t)b * K_ + kk) * H_ + h0];
        const float4 v0 = vp[0], v1 = vp[1];
        const float vr[8] = {v0.x, v0.y, v0.z, v0.w, v1.x, v1.y, v1.z, v1.w};
        const float a0 = sc[0][kk], a1 = sc[1][kk];
        #pragma unroll
        for (int j = 0; j < 8; ++j) {
            c0[j] = __builtin_fmaf(a0, vr[j], c0[j]);
            c1[j] = __builtin_fmaf(a1, vr[j], c1[j]);
        }
    }

    // 3-level tree reduce over 8 waves
    #define PARK(s)                                                         \
        do {                                                                \
            float* d0 = &ctxp[s][0][h0];                                    \
            float* d1 = &ctxp[s][1][h0];                                    \
            ((float4*)d0)[0] = make_float4(c0[0], c0[1], c0[2], c0[3]);     \
            ((float4*)d0)[1] = make_float4(c0[4], c0[5], c0[6], c0[7]);     \
            ((float4*)d1)[0] = make_float4(c1[0], c1[1], c1[2], c1[3]);     \
            ((float4*)d1)[1] = make_float4(c1[4], c1[5], c1[6], c1[7]);     \
        } while (0)
    #define FOLD(s)                                                         \
        do {                                                                \
            const float* d0 = &ctxp[s][0][h0];                              \
            const float* d1 = &ctxp[s][1][h0];                              \
            _Pragma("unroll")                                               \
            for (int j = 0; j < 8; ++j) { c0[j] += d0[j]; c1[j] += d1[j]; } \
        } while (0)

    if (wave >= 4) PARK(wave - 4);
    __syncthreads();
    if (wave < 4) FOLD(wave);
    __syncthreads();
    if (wave == 2 || wave == 3) PARK(wave - 2);
    __syncthreads();
    if (wave < 2) FOLD(wave);
    __syncthreads();
    if (wave == 1) PARK(1);
    __syncthreads();
    if (wave == 0) {
        FOLD(1);
        float* o0 = &out[((size_t)b * Q_ + q0 + 0) * H_ + h0];
        float* o1 = &out[((size_t)b * Q_ + q0 + 1) * H_ + h0];
        ((float4*)o0)[0] = make_float4(c0[0], c0[1], c0[2], c0[3]);
        ((float4*)o0)[1] = make_float4(c0[4], c0[5], c0[6], c0[7]);
        ((float4*)o1)[0] = make_float4(c1[0], c1[1], c1[2], c1[3]);
        ((float4*)o1)[1] = make_float4(c1[4], c1[5], c1[6], c1[7]);
    }
    #undef PARK
    #undef FOLD
}

// ---------------------------------------------------------------------------
extern "C" void kernel_launch(void* const* d_in, const int* in_sizes, int n_in,
                              void* d_out, int out_size, void* d_ws, size_t ws_size,
                              hipStream_t stream)
{
    const float* query = (const float*)d_in[0];
    const float* key   = (const float*)d_in[1];
    const float* value = (const float*)d_in[2];
    const int*   vlen  = (const int*)  d_in[3];
    const float* Wq    = (const float*)d_in[4];
    const float* Wk    = (const float*)d_in[5];
    const float* wv    = (const float*)d_in[6];
    float*       outp  = (float*)d_out;

    float* EqBuf  = (float*)d_ws;                 // [B*Q, H] = 2 MB (e^{2q'})
    float* EkTBuf = EqBuf + (size_t)B_ * Q_ * H_; // [B, H, K] = 2 MB (e^{2k'}, transposed)

    dim3 g1(32, 8);                               // 256 blocks, 256 threads
    proj_kernel<<<g1, 256, 0, stream>>>(query, key, Wq, Wk, EqBuf, EkTBuf, vlen);

    dim3 g2(Q_ / 2, B_);                          // (128, 4), 512 threads
    fused_attn<<<g2, 512, 0, stream>>>(EqBuf, EkTBuf, value, vlen, wv, outp);
}

// Round 9
// 37.114 us; speedup vs baseline: 2.1973x; 1.0827x over previous
//
#include <hip/hip_runtime.h>
#include <hip/hip_bf16.h>

// Problem constants: B=4, Q=256, K=256, H=512
#define B_ 4
#define Q_ 256
#define K_ 256
#define H_ 512
#define NEG (-1e9f)
// 2*log2(e): exp2(PRESCALE*x) = e^{2x}
#define PRESCALE 2.885390081777927f

typedef _Float16 half8 __attribute__((ext_vector_type(8)));
typedef float    f32x4 __attribute__((ext_vector_type(4)));

// ---------------------------------------------------------------------------
// Kernel 1: f16 MFMA projection GEMM + EXP epilogue (r8 structure, deepened).
//   z=0: Eq[b][q][h]  = exp2(PRESCALE * (query@Wq))   row-major
//   z=1: EkT[b][h][k] = exp2(PRESCALE * (key@Wk))     transposed output
// 64x64 tile, K-step 64, 512 thr (8 waves = 2/SIMD at 2 blocks/CU),
// double-buffered LDS, ONE barrier per K-iter (write-other-buf discipline:
// write(i+2) only happens after barrier(i+1), which all waves pass only
// after finishing compute(i) on that buffer).
// Wave (mw = w>>1, nw = w&1) owns 16-row x 32-col sub-tile: 2 ks x 2 nt MFMA.
// z=1 swaps mfma operands so D = [h][k] -> coalesced EkT stores, no bounce.
// Masked key tiles (k0 >= valid_len[b]) skipped.
// ---------------------------------------------------------------------------
__global__ __launch_bounds__(512) void proj_kernel(
    const float* __restrict__ Xq, const float* __restrict__ Xk,
    const float* __restrict__ Wq, const float* __restrict__ Wk,
    float* __restrict__ Eq, float* __restrict__ EkT,
    const int* __restrict__ vlen)
{
    const int bx   = blockIdx.x;          // 0..31
    const int z    = bx >> 4;             // 0 = q, 1 = k
    const int row0 = (bx & 15) * 64;      // X row base (q-row or b*256+k)
    const int bb   = row0 >> 8;
    const int k0   = row0 & 255;
    if (z && k0 >= vlen[bb]) return;      // masked kp cols never read downstream

    const float* X = z ? Xk : Xq;
    const float* W = z ? Wk : Wq;

    // [buf][slab 0..7][row 0..64(pad to 65)][j 0..7]; slab = k-group of 8
    __shared__ _Float16 Xl[2][8 * 520];
    __shared__ _Float16 Wl[2][8 * 520];

    const int col0 = blockIdx.y * 64;     // W col base (= h base)
    const int t    = threadIdx.x;
    const int lane = t & 63;
    const int wave = t >> 6;              // 0..7
    const int mw   = wave >> 1;           // 0..3 -> A-side 16-row strip
    const int nw   = wave & 1;            // 0..1 -> B-side 32-col half
    const int m    = lane & 15;
    const int kgl  = lane >> 4;           // frag k-group

    // staging maps (per K-step-64 chunk)
    const int xr = t >> 3;                // X row 0..63
    const int xg = t & 7;                 // X k-group 0..7
    const int wc = t & 63;                // W col 0..63
    const int wg = t >> 6;                // W k-group 0..7

    f32x4 acc[2] = {};

    // prologue: load chunk 0 into registers
    float4 xv0 = *(const float4*)&X[(size_t)(row0 + xr) * H_ + xg * 8];
    float4 xv1 = *(const float4*)&X[(size_t)(row0 + xr) * H_ + xg * 8 + 4];
    float wv8[8];
    #pragma unroll
    for (int i = 0; i < 8; ++i)
        wv8[i] = W[(size_t)(wg * 8 + i) * H_ + col0 + wc];

    for (int it = 0; it < 8; ++it) {
        const int buf = it & 1;
        // store staged regs to LDS (f32 -> f16)
        {
            half8 hx;
            hx[0] = (_Float16)xv0.x; hx[1] = (_Float16)xv0.y;
            hx[2] = (_Float16)xv0.z; hx[3] = (_Float16)xv0.w;
            hx[4] = (_Float16)xv1.x; hx[5] = (_Float16)xv1.y;
            hx[6] = (_Float16)xv1.z; hx[7] = (_Float16)xv1.w;
            *(half8*)&Xl[buf][xg * 520 + xr * 8] = hx;
            half8 hw;
            #pragma unroll
            for (int i = 0; i < 8; ++i) hw[i] = (_Float16)wv8[i];
            *(half8*)&Wl[buf][wg * 520 + wc * 8] = hw;
        }
        __syncthreads();
        if (it < 7) {                     // prefetch next chunk (hidden by mfma)
            const int kk = (it + 1) * 64;
            xv0 = *(const float4*)&X[(size_t)(row0 + xr) * H_ + kk + xg * 8];
            xv1 = *(const float4*)&X[(size_t)(row0 + xr) * H_ + kk + xg * 8 + 4];
            #pragma unroll
            for (int i = 0; i < 8; ++i)
                wv8[i] = W[(size_t)(kk + wg * 8 + i) * H_ + col0 + wc];
        }
        // compute: z=0: D[q][h] = X·W ; z=1: D[h][k] = W^T·X^T (swap operands)
        const _Float16* Asrc = z ? &Wl[buf][0] : &Xl[buf][0];
        const _Float16* Bsrc = z ? &Xl[buf][0] : &Wl[buf][0];
        #pragma unroll
        for (int ks = 0; ks < 2; ++ks) {
            const int slab = (ks * 4 + kgl) * 520;
            const half8 af = *(const half8*)&Asrc[slab + (16 * mw + m) * 8];
            #pragma unroll
            for (int nt = 0; nt < 2; ++nt) {
                const half8 bf =
                    *(const half8*)&Bsrc[slab + (nw * 32 + nt * 16 + m) * 8];
                acc[nt] = __builtin_amdgcn_mfma_f32_16x16x32_f16(af, bf, acc[nt], 0, 0, 0);
            }
        }
    }

    // epilogue: exp2(PRESCALE * acc); C/D: col = lane&15, row = (lane>>4)*4+r
    const int rloc = 16 * mw + kgl * 4;   // row-dim base (q-row or h)
    if (!z) {
        #pragma unroll
        for (int nt = 0; nt < 2; ++nt) {
            const int gcol = col0 + nw * 32 + nt * 16 + m;
            #pragma unroll
            for (int r = 0; r < 4; ++r)
                Eq[(size_t)(row0 + rloc + r) * H_ + gcol] =
                    __builtin_amdgcn_exp2f(acc[nt][r] * PRESCALE);
        }
    } else {
        #pragma unroll
        for (int nt = 0; nt < 2; ++nt) {
            const int gk = k0 + nw * 32 + nt * 16 + m;   // D col = k (coalesced)
            #pragma unroll
            for (int r = 0; r < 4; ++r)
                EkT[((size_t)bb * H_ + col0 + rloc + r) * K_ + gk] =
                    __builtin_amdgcn_exp2f(acc[nt][r] * PRESCALE);
        }
    }
}

// ---------------------------------------------------------------------------
// Kernel 2: fused scores -> masked softmax -> context.
// grid = (Q/2, B) = (128, 4), block = 512 (8 waves) -> 2 blocks/CU.
// Score phase: wave w owns k-band [32w,32w+32), whole-wave skip if >= valid.
//   lane = (ho = lane>>3, kg = lane&7); thread owns 2 q x 4 k, h-slice
//   {ho+8s}. Ek b128 global loads, 2-DEEP group prefetch (12 float4 in
//   flight covers L2/HBM latency). eq/wm LDS repacked as [ho][s][qi]
//   (pads 132/68 words: 16B-aligned, bank-stride 4 -> conflict-free) so a
//   group needs only 3 b128 broadcast reads (was 8 ops).
//   acc = fma(wm, rcp(fma(eq, ek, 1)), acc); 3 shfl_xor fold ho groups.
// Softmax: waves 0,1. Context: wave w owns its 32-k band, LDS tree reduce.
// ---------------------------------------------------------------------------
__global__ __launch_bounds__(512) void fused_attn(
    const float* __restrict__ Eq, const float* __restrict__ EkT,
    const float* __restrict__ value, const int* __restrict__ vlen,
    const float* __restrict__ wv, float* __restrict__ out)
{
    const int qt = blockIdx.x;        // 0..127
    const int b  = blockIdx.y;        // 0..3
    const int q0 = qt * 2;
    const int t    = threadIdx.x;
    const int wave = t >> 6;          // 0..7
    const int lane = t & 63;

    __shared__ float eqh2[8 * 132];   // [ho][s*2+qi], 4.2 KB
    __shared__ float wm2[8 * 68];     // [ho][s], 2.2 KB  (-2 * wv)
    __shared__ float sc[2][K_];       // 2 KB
    __shared__ float ctxp[4][2][H_];  // 16 KB reduce scratch

    const int valid = vlen[b];

    // ---- one-time staging: eq (repacked) + wm (repacked) ----
    if (t < 256) {
        const int qi = t >> 7, p4 = (t & 127) * 4;
        const float4 v = *(const float4*)&Eq[((size_t)b * Q_ + q0 + qi) * H_ + p4];
        const float vv[4] = {v.x, v.y, v.z, v.w};
        #pragma unroll
        for (int j = 0; j < 4; ++j) {
            const int h = p4 + j;
            eqh2[(h & 7) * 132 + (h >> 3) * 2 + qi] = vv[j];
        }
    } else if (t < 384) {
        const int i = (t - 256) * 4;
        const float4 w = *(const float4*)&wv[i];
        const float ww[4] = {w.x, w.y, w.z, w.w};
        #pragma unroll
        for (int j = 0; j < 4; ++j) {
            const int h = i + j;
            wm2[(h & 7) * 68 + (h >> 3)] = -2.f * ww[j];
        }
    }
    __syncthreads();

    // ---- score phase ----
    const int band = wave * 32;
    const int ho   = lane >> 3;       // h offset 0..7
    const int kg   = lane & 7;        // k group 0..7
    const int kq   = band + kg * 4;   // this thread's first k

    if (band < valid) {
        const float* ekp = EkT + ((size_t)b * H_ + ho) * K_ + kq;
        float a0[4] = {}, a1[4] = {};
        float4 pe[4], n1[4], n2[4];
        #pragma unroll
        for (int p = 0; p < 4; ++p)
            pe[p] = *(const float4*)(ekp + (size_t)p * 8 * K_);
        #pragma unroll
        for (int p = 0; p < 4; ++p)
            n1[p] = *(const float4*)(ekp + (size_t)(4 + p) * 8 * K_);

        for (int g = 0; g < 16; ++g) {        // 16 groups x 4 h-steps
            if (g < 14) {
                #pragma unroll
                for (int p = 0; p < 4; ++p)
                    n2[p] = *(const float4*)(ekp + (size_t)((g + 2) * 4 + p) * 8 * K_);
            }
            const float4 eqA = *(const float4*)&eqh2[ho * 132 + g * 8];
            const float4 eqB = *(const float4*)&eqh2[ho * 132 + g * 8 + 4];
            const float4 wv4 = *(const float4*)&wm2[ho * 68 + g * 4];
            const float eq0[4] = {eqA.x, eqA.z, eqB.x, eqB.z};
            const float eq1[4] = {eqA.y, eqA.w, eqB.y, eqB.w};
            const float wmp[4] = {wv4.x, wv4.y, wv4.z, wv4.w};
            #pragma unroll
            for (int p = 0; p < 4; ++p) {
                const float ek4[4] = {pe[p].x, pe[p].y, pe[p].z, pe[p].w};
                #pragma unroll
                for (int j = 0; j < 4; ++j) {
                    const float g0 = __builtin_fmaf(eq0[p], ek4[j], 1.0f);
                    a0[j] = __builtin_fmaf(wmp[p], __builtin_amdgcn_rcpf(g0), a0[j]);
                    const float g1 = __builtin_fmaf(eq1[p], ek4[j], 1.0f);
                    a1[j] = __builtin_fmaf(wmp[p], __builtin_amdgcn_rcpf(g1), a1[j]);
                }
            }
            #pragma unroll
            for (int p = 0; p < 4; ++p) { pe[p] = n1[p]; n1[p] = n2[p]; }
        }
        // combine h-partials across ho groups (lane bits 3..5)
        #pragma unroll
        for (int d = 8; d < 64; d <<= 1) {
            #pragma unroll
            for (int j = 0; j < 4; ++j) {
                a0[j] += __shfl_xor(a0[j], d);
                a1[j] += __shfl_xor(a1[j], d);
            }
        }
        if (ho == 0) {
            *(float4*)&sc[0][kq] = make_float4(a0[0], a0[1], a0[2], a0[3]);
            *(float4*)&sc[1][kq] = make_float4(a1[0], a1[1], a1[2], a1[3]);
        }
    }
    __syncthreads();

    // ---- masked softmax (waves 0,1; row = wave) ----
    if (wave < 2) {
        const int q = wave;
        if (valid == 0) {
            #pragma unroll
            for (int j = 0; j < 4; ++j) sc[q][lane + 64 * j] = 1.0f / K_;
        } else {
            float sv[4], mx = -3e38f;
            #pragma unroll
            for (int j = 0; j < 4; ++j) {
                const int kk = lane + 64 * j;
                const float s = (kk < valid) ? sc[q][kk] : NEG;
                sv[j] = s;
                mx = fmaxf(mx, s);
            }
            #pragma unroll
            for (int d = 32; d; d >>= 1) mx = fmaxf(mx, __shfl_xor(mx, d));
            float ev[4], sum = 0.f;
            #pragma unroll
            for (int j = 0; j < 4; ++j) { ev[j] = __expf(sv[j] - mx); sum += ev[j]; }
            #pragma unroll
            for (int d = 32; d; d >>= 1) sum += __shfl_xor(sum, d);
            const float inv = 1.0f / sum;
            #pragma unroll
            for (int j = 0; j < 4; ++j) sc[q][lane + 64 * j] = ev[j] * inv;
        }
    }
    __syncthreads();

    // ---- context: wave w owns k in [32w, 32w+32) ----
    const int klim = (valid == 0) ? K_ : valid;
    const int kb   = wave * 32;
    const int kend = min(32, klim - kb);
    const int h0   = lane * 8;

    float c0[8] = {}, c1[8] = {};
    for (int kc = 0; kc < kend; ++kc) {
        const int kk = kb + kc;
        const float4* vp = (const float4*)&value[((size_t)b * K_ + kk) * H_ + h0];
        const float4 v0 = vp[0], v1 = vp[1];
        const float vr[8] = {v0.x, v0.y, v0.z, v0.w, v1.x, v1.y, v1.z, v1.w};
        const float a0 = sc[0][kk], a1 = sc[1][kk];
        #pragma unroll
        for (int j = 0; j < 8; ++j) {
            c0[j] = __builtin_fmaf(a0, vr[j], c0[j]);
            c1[j] = __builtin_fmaf(a1, vr[j], c1[j]);
        }
    }

    // 3-level tree reduce over 8 waves
    #define PARK(s)                                                         \
        do {                                                                \
            float* d0 = &ctxp[s][0][h0];                                    \
            float* d1 = &ctxp[s][1][h0];                                    \
            ((float4*)d0)[0] = make_float4(c0[0], c0[1], c0[2], c0[3]);     \
            ((float4*)d0)[1] = make_float4(c0[4], c0[5], c0[6], c0[7]);     \
            ((float4*)d1)[0] = make_float4(c1[0], c1[1], c1[2], c1[3]);     \
            ((float4*)d1)[1] = make_float4(c1[4], c1[5], c1[6], c1[7]);     \
        } while (0)
    #define FOLD(s)                                                         \
        do {                                                                \
            const float* d0 = &ctxp[s][0][h0];                              \
            const float* d1 = &ctxp[s][1][h0];                              \
            _Pragma("unroll")                                               \
            for (int j = 0; j < 8; ++j) { c0[j] += d0[j]; c1[j] += d1[j]; } \
        } while (0)

    if (wave >= 4) PARK(wave - 4);
    __syncthreads();
    if (wave < 4) FOLD(wave);
    __syncthreads();
    if (wave == 2 || wave == 3) PARK(wave - 2);
    __syncthreads();
    if (wave < 2) FOLD(wave);
    __syncthreads();
    if (wave == 1) PARK(1);
    __syncthreads();
    if (wave == 0) {
        FOLD(1);
        float* o0 = &out[((size_t)b * Q_ + q0 + 0) * H_ + h0];
        float* o1 = &out[((size_t)b * Q_ + q0 + 1) * H_ + h0];
        ((float4*)o0)[0] = make_float4(c0[0], c0[1], c0[2], c0[3]);
        ((float4*)o0)[1] = make_float4(c0[4], c0[5], c0[6], c0[7]);
        ((float4*)o1)[0] = make_float4(c1[0], c1[1], c1[2], c1[3]);
        ((float4*)o1)[1] = make_float4(c1[4], c1[5], c1[6], c1[7]);
    }
    #undef PARK
    #undef FOLD
}

// ---------------------------------------------------------------------------
extern "C" void kernel_launch(void* const* d_in, const int* in_sizes, int n_in,
                              void* d_out, int out_size, void* d_ws, size_t ws_size,
                              hipStream_t stream)
{
    const float* query = (const float*)d_in[0];
    const float* key   = (const float*)d_in[1];
    const float* value = (const float*)d_in[2];
    const int*   vlen  = (const int*)  d_in[3];
    const float* Wq    = (const float*)d_in[4];
    const float* Wk    = (const float*)d_in[5];
    const float* wv    = (const float*)d_in[6];
    float*       outp  = (float*)d_out;

    float* EqBuf  = (float*)d_ws;                 // [B*Q, H] = 2 MB (e^{2q'})
    float* EkTBuf = EqBuf + (size_t)B_ * Q_ * H_; // [B, H, K] = 2 MB (e^{2k'}, transposed)

    dim3 g1(32, 8);                               // 256 blocks, 512 threads
    proj_kernel<<<g1, 512, 0, stream>>>(query, key, Wq, Wk, EqBuf, EkTBuf, vlen);

    dim3 g2(Q_ / 2, B_);                          // (128, 4), 512 threads
    fused_attn<<<g2, 512, 0, stream>>>(EqBuf, EkTBuf, value, vlen, wv, outp);
}

// Round 10
// 36.651 us; speedup vs baseline: 2.2250x; 1.0126x over previous
//
#include <hip/hip_runtime.h>
#include <hip/hip_bf16.h>

// Problem constants: B=4, Q=256, K=256, H=512
#define B_ 4
#define Q_ 256
#define K_ 256
#define H_ 512
#define NEG (-1e9f)
// 2*log2(e): exp2(PRESCALE*x) = e^{2x}
#define PRESCALE 2.885390081777927f

typedef _Float16 half8 __attribute__((ext_vector_type(8)));
typedef float    f32x4 __attribute__((ext_vector_type(4)));

// ---------------------------------------------------------------------------
// Kernel 1: f16 MFMA projection GEMM + EXP epilogue (unchanged from r9).
//   z=0: Eq[b][q][h]  = exp2(PRESCALE * (query@Wq))   row-major
//   z=1: EkT[b][h][k] = exp2(PRESCALE * (key@Wk))     transposed output
// 64x64 tile, K-step 64, 512 thr, double-buffered LDS, 1 barrier/iter.
// ---------------------------------------------------------------------------
__global__ __launch_bounds__(512) void proj_kernel(
    const float* __restrict__ Xq, const float* __restrict__ Xk,
    const float* __restrict__ Wq, const float* __restrict__ Wk,
    float* __restrict__ Eq, float* __restrict__ EkT,
    const int* __restrict__ vlen)
{
    const int bx   = blockIdx.x;          // 0..31
    const int z    = bx >> 4;             // 0 = q, 1 = k
    const int row0 = (bx & 15) * 64;      // X row base (q-row or b*256+k)
    const int bb   = row0 >> 8;
    const int k0   = row0 & 255;
    if (z && k0 >= vlen[bb]) return;      // masked kp cols never read downstream

    const float* X = z ? Xk : Xq;
    const float* W = z ? Wk : Wq;

    __shared__ _Float16 Xl[2][8 * 520];
    __shared__ _Float16 Wl[2][8 * 520];

    const int col0 = blockIdx.y * 64;     // W col base (= h base)
    const int t    = threadIdx.x;
    const int lane = t & 63;
    const int wave = t >> 6;              // 0..7
    const int mw   = wave >> 1;           // 0..3 -> A-side 16-row strip
    const int nw   = wave & 1;            // 0..1 -> B-side 32-col half
    const int m    = lane & 15;
    const int kgl  = lane >> 4;           // frag k-group

    const int xr = t >> 3;                // X row 0..63
    const int xg = t & 7;                 // X k-group 0..7
    const int wc = t & 63;                // W col 0..63
    const int wg = t >> 6;                // W k-group 0..7

    f32x4 acc[2] = {};

    float4 xv0 = *(const float4*)&X[(size_t)(row0 + xr) * H_ + xg * 8];
    float4 xv1 = *(const float4*)&X[(size_t)(row0 + xr) * H_ + xg * 8 + 4];
    float wv8[8];
    #pragma unroll
    for (int i = 0; i < 8; ++i)
        wv8[i] = W[(size_t)(wg * 8 + i) * H_ + col0 + wc];

    for (int it = 0; it < 8; ++it) {
        const int buf = it & 1;
        {
            half8 hx;
            hx[0] = (_Float16)xv0.x; hx[1] = (_Float16)xv0.y;
            hx[2] = (_Float16)xv0.z; hx[3] = (_Float16)xv0.w;
            hx[4] = (_Float16)xv1.x; hx[5] = (_Float16)xv1.y;
            hx[6] = (_Float16)xv1.z; hx[7] = (_Float16)xv1.w;
            *(half8*)&Xl[buf][xg * 520 + xr * 8] = hx;
            half8 hw;
            #pragma unroll
            for (int i = 0; i < 8; ++i) hw[i] = (_Float16)wv8[i];
            *(half8*)&Wl[buf][wg * 520 + wc * 8] = hw;
        }
        __syncthreads();
        if (it < 7) {
            const int kk = (it + 1) * 64;
            xv0 = *(const float4*)&X[(size_t)(row0 + xr) * H_ + kk + xg * 8];
            xv1 = *(const float4*)&X[(size_t)(row0 + xr) * H_ + kk + xg * 8 + 4];
            #pragma unroll
            for (int i = 0; i < 8; ++i)
                wv8[i] = W[(size_t)(kk + wg * 8 + i) * H_ + col0 + wc];
        }
        const _Float16* Asrc = z ? &Wl[buf][0] : &Xl[buf][0];
        const _Float16* Bsrc = z ? &Xl[buf][0] : &Wl[buf][0];
        #pragma unroll
        for (int ks = 0; ks < 2; ++ks) {
            const int slab = (ks * 4 + kgl) * 520;
            const half8 af = *(const half8*)&Asrc[slab + (16 * mw + m) * 8];
            #pragma unroll
            for (int nt = 0; nt < 2; ++nt) {
                const half8 bf =
                    *(const half8*)&Bsrc[slab + (nw * 32 + nt * 16 + m) * 8];
                acc[nt] = __builtin_amdgcn_mfma_f32_16x16x32_f16(af, bf, acc[nt], 0, 0, 0);
            }
        }
    }

    const int rloc = 16 * mw + kgl * 4;   // row-dim base (q-row or h)
    if (!z) {
        #pragma unroll
        for (int nt = 0; nt < 2; ++nt) {
            const int gcol = col0 + nw * 32 + nt * 16 + m;
            #pragma unroll
            for (int r = 0; r < 4; ++r)
                Eq[(size_t)(row0 + rloc + r) * H_ + gcol] =
                    __builtin_amdgcn_exp2f(acc[nt][r] * PRESCALE);
        }
    } else {
        #pragma unroll
        for (int nt = 0; nt < 2; ++nt) {
            const int gk = k0 + nw * 32 + nt * 16 + m;   // D col = k (coalesced)
            #pragma unroll
            for (int r = 0; r < 4; ++r)
                EkT[((size_t)bb * H_ + col0 + rloc + r) * K_ + gk] =
                    __builtin_amdgcn_exp2f(acc[nt][r] * PRESCALE);
        }
    }
}

// ---------------------------------------------------------------------------
// Kernel 2: fused scores -> masked softmax -> context.  TQ = 4 q-rows/block.
// grid = (Q/4, B) = (64, 4) = 256 blocks, 512 thr (8 waves) -> 1 block/CU.
// Halves Ek and value L2 traffic vs TQ=2 (same trans/VALU work per CU).
// Score: wave w owns k-band [32w,+32), whole-wave skip if >= valid.
//   lane = (ho = lane>>3, kg = lane&7); thread owns 4 q x 4 k, h-slice
//   {ho+8s}. Ek b128 global loads, 2-deep group prefetch. eqh2 packed
//   [ho][s][qi] (stride 260 -> 16B-aligned, bank-offset 4*ho) so ONE b128
//   broadcast yields all 4 q values per h; wm2 [ho][s] as before.
//   acc[qi][j] = fma(wm, rcp(fma(eq[qi], ek[j], 1)), .); 3 shfl_xor folds.
// Softmax: waves 0..3 (row = wave). Context: wave w owns its 32-k band,
//   3-level LDS tree reduce (ctxp 32 KB), wave 0 writes 4 rows.
// ---------------------------------------------------------------------------
__global__ __launch_bounds__(512) void fused_attn(
    const float* __restrict__ Eq, const float* __restrict__ EkT,
    const float* __restrict__ value, const int* __restrict__ vlen,
    const float* __restrict__ wv, float* __restrict__ out)
{
    const int qt = blockIdx.x;        // 0..63
    const int b  = blockIdx.y;        // 0..3
    const int q0 = qt * 4;
    const int t    = threadIdx.x;
    const int wave = t >> 6;          // 0..7
    const int lane = t & 63;

    __shared__ float eqh2[8 * 260];   // [ho][s*4+qi], 8.3 KB
    __shared__ float wm2[8 * 68];     // [ho][s], 2.2 KB  (-2 * wv)
    __shared__ float sc[4][K_];       // 4 KB
    __shared__ float ctxp[4][4][H_];  // 32 KB reduce scratch

    const int valid = vlen[b];

    // ---- one-time staging: eq (repacked, 4 q rows) + wm (repacked) ----
    {
        const int qi = t >> 7, p4 = (t & 127) * 4;
        const float4 v = *(const float4*)&Eq[((size_t)b * Q_ + q0 + qi) * H_ + p4];
        const float vv[4] = {v.x, v.y, v.z, v.w};
        const int sbase = (p4 >> 3) * 4;     // p4+j stays in same 8-block
        #pragma unroll
        for (int j = 0; j < 4; ++j)
            eqh2[((p4 & 7) + j) * 260 + sbase + qi] = vv[j];
        if (t < 128) {
            const float4 w = *(const float4*)&wv[t * 4];
            const float ww[4] = {w.x, w.y, w.z, w.w};
            #pragma unroll
            for (int j = 0; j < 4; ++j) {
                const int h = t * 4 + j;
                wm2[(h & 7) * 68 + (h >> 3)] = -2.f * ww[j];
            }
        }
    }
    __syncthreads();

    // ---- score phase ----
    const int band = wave * 32;
    const int ho   = lane >> 3;       // h offset 0..7
    const int kg   = lane & 7;        // k group 0..7
    const int kq   = band + kg * 4;   // this thread's first k

    if (band < valid) {
        const float* ekp = EkT + ((size_t)b * H_ + ho) * K_ + kq;
        float acc0[4] = {}, acc1[4] = {}, acc2[4] = {}, acc3[4] = {};
        float4 pe[4], n1[4], n2[4];
        #pragma unroll
        for (int p = 0; p < 4; ++p)
            pe[p] = *(const float4*)(ekp + (size_t)p * 8 * K_);
        #pragma unroll
        for (int p = 0; p < 4; ++p)
            n1[p] = *(const float4*)(ekp + (size_t)(4 + p) * 8 * K_);

        for (int g = 0; g < 16; ++g) {        // 16 groups x 4 h-steps
            if (g < 14) {
                #pragma unroll
                for (int p = 0; p < 4; ++p)
                    n2[p] = *(const float4*)(ekp + (size_t)((g + 2) * 4 + p) * 8 * K_);
            }
            const float4 wv4 = *(const float4*)&wm2[ho * 68 + g * 4];
            const float wmp[4] = {wv4.x, wv4.y, wv4.z, wv4.w};
            #pragma unroll
            for (int p = 0; p < 4; ++p) {
                const float4 eq4 = *(const float4*)&eqh2[ho * 260 + (g * 4 + p) * 4];
                const float ek4[4] = {pe[p].x, pe[p].y, pe[p].z, pe[p].w};
                #pragma unroll
                for (int j = 0; j < 4; ++j) {
                    const float g0 = __builtin_fmaf(eq4.x, ek4[j], 1.0f);
                    acc0[j] = __builtin_fmaf(wmp[p], __builtin_amdgcn_rcpf(g0), acc0[j]);
                    const float g1 = __builtin_fmaf(eq4.y, ek4[j], 1.0f);
                    acc1[j] = __builtin_fmaf(wmp[p], __builtin_amdgcn_rcpf(g1), acc1[j]);
                    const float g2 = __builtin_fmaf(eq4.z, ek4[j], 1.0f);
                    acc2[j] = __builtin_fmaf(wmp[p], __builtin_amdgcn_rcpf(g2), acc2[j]);
                    const float g3 = __builtin_fmaf(eq4.w, ek4[j], 1.0f);
                    acc3[j] = __builtin_fmaf(wmp[p], __builtin_amdgcn_rcpf(g3), acc3[j]);
                }
            }
            #pragma unroll
            for (int p = 0; p < 4; ++p) { pe[p] = n1[p]; n1[p] = n2[p]; }
        }
        // combine h-partials across ho groups (lane bits 3..5)
        #pragma unroll
        for (int d = 8; d < 64; d <<= 1) {
            #pragma unroll
            for (int j = 0; j < 4; ++j) {
                acc0[j] += __shfl_xor(acc0[j], d);
                acc1[j] += __shfl_xor(acc1[j], d);
                acc2[j] += __shfl_xor(acc2[j], d);
                acc3[j] += __shfl_xor(acc3[j], d);
            }
        }
        if (ho == 0) {
            *(float4*)&sc[0][kq] = make_float4(acc0[0], acc0[1], acc0[2], acc0[3]);
            *(float4*)&sc[1][kq] = make_float4(acc1[0], acc1[1], acc1[2], acc1[3]);
            *(float4*)&sc[2][kq] = make_float4(acc2[0], acc2[1], acc2[2], acc2[3]);
            *(float4*)&sc[3][kq] = make_float4(acc3[0], acc3[1], acc3[2], acc3[3]);
        }
    }
    __syncthreads();

    // ---- masked softmax (waves 0..3; row = wave) ----
    if (wave < 4) {
        const int q = wave;
        if (valid == 0) {
            #pragma unroll
            for (int j = 0; j < 4; ++j) sc[q][lane + 64 * j] = 1.0f / K_;
        } else {
            float sv[4], mx = -3e38f;
            #pragma unroll
            for (int j = 0; j < 4; ++j) {
                const int kk = lane + 64 * j;
                const float s = (kk < valid) ? sc[q][kk] : NEG;
                sv[j] = s;
                mx = fmaxf(mx, s);
            }
            #pragma unroll
            for (int d = 32; d; d >>= 1) mx = fmaxf(mx, __shfl_xor(mx, d));
            float ev[4], sum = 0.f;
            #pragma unroll
            for (int j = 0; j < 4; ++j) { ev[j] = __expf(sv[j] - mx); sum += ev[j]; }
            #pragma unroll
            for (int d = 32; d; d >>= 1) sum += __shfl_xor(sum, d);
            const float inv = 1.0f / sum;
            #pragma unroll
            for (int j = 0; j < 4; ++j) sc[q][lane + 64 * j] = ev[j] * inv;
        }
    }
    __syncthreads();

    // ---- context: wave w owns k in [32w, 32w+32), 4 q rows ----
    const int klim = (valid == 0) ? K_ : valid;
    const int kb   = wave * 32;
    const int kend = min(32, klim - kb);
    const int h0   = lane * 8;

    float c[4][8] = {};
    for (int kc = 0; kc < kend; ++kc) {
        const int kk = kb + kc;
        const float4* vp = (const float4*)&value[((size_t)b * K_ + kk) * H_ + h0];
        const float4 v0 = vp[0], v1 = vp[1];
        const float vr[8] = {v0.x, v0.y, v0.z, v0.w, v1.x, v1.y, v1.z, v1.w};
        const float a0 = sc[0][kk], a1 = sc[1][kk], a2 = sc[2][kk], a3 = sc[3][kk];
        #pragma unroll
        for (int j = 0; j < 8; ++j) {
            c[0][j] = __builtin_fmaf(a0, vr[j], c[0][j]);
            c[1][j] = __builtin_fmaf(a1, vr[j], c[1][j]);
            c[2][j] = __builtin_fmaf(a2, vr[j], c[2][j]);
            c[3][j] = __builtin_fmaf(a3, vr[j], c[3][j]);
        }
    }

    // 3-level tree reduce over 8 waves (4 q rows)
    #define PARK(s)                                                           \
        do {                                                                  \
            _Pragma("unroll")                                                 \
            for (int qi = 0; qi < 4; ++qi) {                                  \
                float* d = &ctxp[s][qi][h0];                                  \
                ((float4*)d)[0] = make_float4(c[qi][0], c[qi][1], c[qi][2], c[qi][3]); \
                ((float4*)d)[1] = make_float4(c[qi][4], c[qi][5], c[qi][6], c[qi][7]); \
            }                                                                 \
        } while (0)
    #define FOLD(s)                                                           \
        do {                                                                  \
            _Pragma("unroll")                                                 \
            for (int qi = 0; qi < 4; ++qi) {                                  \
                const float* d = &ctxp[s][qi][h0];                            \
                _Pragma("unroll")                                             \
                for (int j = 0; j < 8; ++j) c[qi][j] += d[j];                 \
            }                                                                 \
        } while (0)

    if (wave >= 4) PARK(wave - 4);
    __syncthreads();
    if (wave < 4) FOLD(wave);
    __syncthreads();
    if (wave == 2 || wave == 3) PARK(wave - 2);
    __syncthreads();
    if (wave < 2) FOLD(wave);
    __syncthreads();
    if (wave == 1) PARK(1);
    __syncthreads();
    if (wave == 0) {
        FOLD(1);
        #pragma unroll
        for (int qi = 0; qi < 4; ++qi) {
            float* o = &out[((size_t)b * Q_ + q0 + qi) * H_ + h0];
            ((float4*)o)[0] = make_float4(c[qi][0], c[qi][1], c[qi][2], c[qi][3]);
            ((float4*)o)[1] = make_float4(c[qi][4], c[qi][5], c[qi][6], c[qi][7]);
        }
    }
    #undef PARK
    #undef FOLD
}

// ---------------------------------------------------------------------------
extern "C" void kernel_launch(void* const* d_in, const int* in_sizes, int n_in,
                              void* d_out, int out_size, void* d_ws, size_t ws_size,
                              hipStream_t stream)
{
    const float* query = (const float*)d_in[0];
    const float* key   = (const float*)d_in[1];
    const float* value = (const float*)d_in[2];
    const int*   vlen  = (const int*)  d_in[3];
    const float* Wq    = (const float*)d_in[4];
    const float* Wk    = (const float*)d_in[5];
    const float* wv    = (const float*)d_in[6];
    float*       outp  = (float*)d_out;

    float* EqBuf  = (float*)d_ws;                 // [B*Q, H] = 2 MB (e^{2q'})
    float* EkTBuf = EqBuf + (size_t)B_ * Q_ * H_; // [B, H, K] = 2 MB (e^{2k'}, transposed)

    dim3 g1(32, 8);                               // 256 blocks, 512 threads
    proj_kernel<<<g1, 512, 0, stream>>>(query, key, Wq, Wk, EqBuf, EkTBuf, vlen);

    dim3 g2(Q_ / 4, B_);                          // (64, 4), 512 threads
    fused_attn<<<g2, 512, 0, stream>>>(EqBuf, EkTBuf, value, vlen, wv, outp);
}